// Round 1
// baseline (708.280 us; speedup 1.0000x reference)
//
#include <hip/hip_runtime.h>
#include <cstdint>
#include <cstddef>

typedef __attribute__((ext_vector_type(8))) short short8;
typedef __attribute__((ext_vector_type(4))) float f32x4;

// ---------- helpers ----------
__device__ __forceinline__ unsigned short f2bf(float x) {
  union { float f; unsigned u; } v; v.f = x;
  unsigned r = (v.u + 0x7FFFu + ((v.u >> 16) & 1u)) >> 16;
  return (unsigned short)r;
}
__device__ __forceinline__ float bf2f(unsigned short u) {
  union { unsigned u; float f; } v; v.u = ((unsigned)u) << 16;
  return v.f;
}

#define GLOAD16(g, l)                                                    \
  __builtin_amdgcn_global_load_lds(                                      \
      (const __attribute__((address_space(1))) unsigned int*)(g),        \
      (__attribute__((address_space(3))) unsigned int*)(l), 16, 0, 0)

// ---------- f32 -> bf16 conversion (memory-bound) ----------
__global__ __launch_bounds__(256) void cvt_f32_bf16(
    const float* __restrict__ in, unsigned short* __restrict__ out, long n) {
  long i = ((long)blockIdx.x * 256 + threadIdx.x) * 8;
  if (i >= n) return;
  const float4* p = (const float4*)(in + i);
  float4 a = p[0], b = p[1];
  short8 r;
  r[0] = (short)f2bf(a.x); r[1] = (short)f2bf(a.y);
  r[2] = (short)f2bf(a.z); r[3] = (short)f2bf(a.w);
  r[4] = (short)f2bf(b.x); r[5] = (short)f2bf(b.y);
  r[6] = (short)f2bf(b.z); r[7] = (short)f2bf(b.w);
  *(short8*)(out + i) = r;
}

// ---------- gemm_bt: C[m,n] = scale * sum_k A[m,k]*B[n,k] ----------
// A: [M,K] bf16 row-major (lda elems), B: [N,K] bf16 row-major (ldb elems).
// 128x128 tile, 4 waves (2x2), BK=64, 16x16x32 bf16 MFMA.
// LDS XOR-swizzle: slot-col ^= (row&7); applied on stage-SOURCE and on READ.
template <bool OUT_BF16>
__global__ __launch_bounds__(256) void gemm_bt(
    const unsigned short* __restrict__ A, int lda,
    const unsigned short* __restrict__ B, int ldb,
    void* __restrict__ C, int ldc,
    int nbn, int K, float scale) {
  __shared__ unsigned short As[128 * 64];
  __shared__ unsigned short Bs[128 * 64];

  // XCD-aware swizzle (grid always a multiple of 8 here)
  unsigned bid = blockIdx.x;
  unsigned cpx = gridDim.x >> 3;
  unsigned swz = (bid & 7u) * cpx + (bid >> 3);
  int bm = (int)(swz / (unsigned)nbn);
  int bn = (int)(swz % (unsigned)nbn);
  int m0 = bm * 128, n0 = bn * 128;

  int t = threadIdx.x;
  int lane = t & 63, wid = t >> 6;
  int wm = wid >> 1, wn = wid & 1;
  int l15 = lane & 15, l4 = lane >> 4;

  // staging: chunk c = i*256 + t ; row = c>>3 (=32*i + t>>3), slot col = c&7
  int srow = t >> 3;
  int scol = t & 7;
  int g = scol ^ (srow & 7);  // inverse-swizzled global chunk col
  const unsigned short* pa = A + (size_t)(m0 + srow) * lda + g * 8;
  const unsigned short* pb = B + (size_t)(n0 + srow) * ldb + g * 8;

  f32x4 acc[4][4] = {};

  for (int k0 = 0; k0 < K; k0 += 64) {
    __syncthreads();
#pragma unroll
    for (int i = 0; i < 4; i++) {
      GLOAD16(pa + (size_t)(32 * i) * lda + k0,
              (char*)As + (size_t)(i * 256 + wid * 64) * 16);
      GLOAD16(pb + (size_t)(32 * i) * ldb + k0,
              (char*)Bs + (size_t)(i * 256 + wid * 64) * 16);
    }
    __syncthreads();
#pragma unroll
    for (int ks = 0; ks < 2; ks++) {
      short8 af[4], bfr[4];
#pragma unroll
      for (int mi = 0; mi < 4; mi++) {
        int r = wm * 64 + mi * 16 + l15;
        int c = ((ks << 2) | l4) ^ (r & 7);
        af[mi] = *(const short8*)((const char*)As + r * 128 + c * 16);
      }
#pragma unroll
      for (int ni = 0; ni < 4; ni++) {
        int r = wn * 64 + ni * 16 + l15;
        int c = ((ks << 2) | l4) ^ (r & 7);
        bfr[ni] = *(const short8*)((const char*)Bs + r * 128 + c * 16);
      }
#pragma unroll
      for (int mi = 0; mi < 4; mi++)
#pragma unroll
        for (int ni = 0; ni < 4; ni++)
          acc[mi][ni] = __builtin_amdgcn_mfma_f32_16x16x32_bf16(
              af[mi], bfr[ni], acc[mi][ni], 0, 0, 0);
    }
  }

#pragma unroll
  for (int mi = 0; mi < 4; mi++)
#pragma unroll
    for (int ni = 0; ni < 4; ni++)
#pragma unroll
      for (int j = 0; j < 4; j++) {
        int row = m0 + wm * 64 + mi * 16 + l4 * 4 + j;
        int col = n0 + wn * 64 + ni * 16 + l15;
        float val = acc[mi][ni][j] * scale;
        if constexpr (OUT_BF16)
          ((unsigned short*)C)[(size_t)row * ldc + col] = f2bf(val);
        else
          ((float*)C)[(size_t)row * ldc + col] = val;
      }
}

// ---------- row softmax over bf16 matrix, in place ----------
// one block per row; 256 threads x 16 elems = 4096 cols
__global__ __launch_bounds__(256) void softmax_rows(unsigned short* S, int ncols) {
  __shared__ float red[8];
  int row = blockIdx.x;
  unsigned short* p = S + (size_t)row * ncols;
  int t = threadIdx.x;
  int lane = t & 63, wid = t >> 6;

  short8 h0 = ((short8*)p)[t * 2];
  short8 h1 = ((short8*)p)[t * 2 + 1];
  float v[16];
#pragma unroll
  for (int j = 0; j < 8; j++) {
    v[j] = bf2f((unsigned short)h0[j]);
    v[8 + j] = bf2f((unsigned short)h1[j]);
  }
  float m = v[0];
#pragma unroll
  for (int j = 1; j < 16; j++) m = fmaxf(m, v[j]);
#pragma unroll
  for (int off = 1; off < 64; off <<= 1) m = fmaxf(m, __shfl_xor(m, off));
  if (lane == 0) red[wid] = m;
  __syncthreads();
  m = fmaxf(fmaxf(red[0], red[1]), fmaxf(red[2], red[3]));

  float e[16], s = 0.f;
#pragma unroll
  for (int j = 0; j < 16; j++) { e[j] = __expf(v[j] - m); s += e[j]; }
#pragma unroll
  for (int off = 1; off < 64; off <<= 1) s += __shfl_xor(s, off);
  if (lane == 0) red[4 + wid] = s;
  __syncthreads();
  float inv = 1.0f / (red[4] + red[5] + red[6] + red[7]);

  short8 o0, o1;
#pragma unroll
  for (int j = 0; j < 8; j++) {
    o0[j] = (short)f2bf(e[j] * inv);
    o1[j] = (short)f2bf(e[8 + j] * inv);
  }
  ((short8*)p)[t * 2] = o0;
  ((short8*)p)[t * 2 + 1] = o1;
}

// ---------- launcher ----------
extern "C" void kernel_launch(void* const* d_in, const int* in_sizes, int n_in,
                              void* d_out, int out_size, void* d_ws, size_t ws_size,
                              hipStream_t stream) {
  (void)in_sizes; (void)n_in; (void)out_size; (void)ws_size;
  const float* x  = (const float*)d_in[0];
  const float* Wq = (const float*)d_in[1];
  const float* Wk = (const float*)d_in[2];
  const float* Wv = (const float*)d_in[3];
  float* out = (float*)d_out;

  const int Bn = 4, S = 4096, D = 1024;
  const size_t MS = (size_t)Bn * S;  // 16384

  char* ws = (char*)d_ws;
  unsigned short* xb  = (unsigned short*)ws; ws += MS * D * 2;          // 33.5MB
  unsigned short* wqb = (unsigned short*)ws; ws += (size_t)D * D * 2;   // 2MB
  unsigned short* wkb = (unsigned short*)ws; ws += (size_t)D * D * 2;
  unsigned short* wvb = (unsigned short*)ws; ws += (size_t)D * D * 2;
  unsigned short* Qb  = (unsigned short*)ws; ws += MS * D * 2;
  unsigned short* Kb  = (unsigned short*)ws; ws += MS * D * 2;
  unsigned short* VTb = (unsigned short*)ws; ws += MS * D * 2;          // [D, B*S]
  unsigned short* Sb  = (unsigned short*)ws; ws += (size_t)S * S * 2;   // per-batch

  // convert inputs to bf16
  cvt_f32_bf16<<<8192, 256, 0, stream>>>(x, xb, (long)MS * D);
  cvt_f32_bf16<<<512, 256, 0, stream>>>(Wq, wqb, (long)D * D);
  cvt_f32_bf16<<<512, 256, 0, stream>>>(Wk, wkb, (long)D * D);
  cvt_f32_bf16<<<512, 256, 0, stream>>>(Wv, wvb, (long)D * D);

  // Q = x @ Wq^T  (M=16384,N=1024,K=1024), same for K
  gemm_bt<true><<<1024, 256, 0, stream>>>(xb, D, wqb, D, Qb, D, 8, D, 1.0f);
  gemm_bt<true><<<1024, 256, 0, stream>>>(xb, D, wkb, D, Kb, D, 8, D, 1.0f);
  // VT = Wv @ x^T  (M=1024,N=16384,K=1024) -> VT[d, b*S+s]
  gemm_bt<true><<<1024, 256, 0, stream>>>(wvb, D, xb, D, VTb, (int)MS, 128, D, 1.0f);

  const float scale = 0.03125f;  // 1/sqrt(1024)
  for (int b = 0; b < Bn; b++) {
    const unsigned short* Qx = Qb + (size_t)b * S * D;
    const unsigned short* Kx = Kb + (size_t)b * S * D;
    // scores = Q K^T * scale  (M=N=4096, K=1024) -> bf16
    gemm_bt<true><<<1024, 256, 0, stream>>>(Qx, D, Kx, D, Sb, S, 32, D, scale);
    softmax_rows<<<4096, 256, 0, stream>>>(Sb, S);
    // out_b = P @ V  via B'[n,k] = VT[n, b*S+k]  (M=4096,N=1024,K=4096)
    gemm_bt<false><<<256, 256, 0, stream>>>(Sb, S, VTb + (size_t)b * S, (int)MS,
                                            out + (size_t)b * S * D, D, 8, S, 1.0f);
  }
}

// Round 2
// 534.857 us; speedup vs baseline: 1.3242x; 1.3242x over previous
//
#include <hip/hip_runtime.h>
#include <cstdint>
#include <cstddef>

typedef __attribute__((ext_vector_type(8))) short short8;
typedef __attribute__((ext_vector_type(4))) float f32x4;

// ---------- helpers ----------
__device__ __forceinline__ unsigned short f2bf(float x) {
  union { float f; unsigned u; } v; v.f = x;
  unsigned r = (v.u + 0x7FFFu + ((v.u >> 16) & 1u)) >> 16;
  return (unsigned short)r;
}
__device__ __forceinline__ float bf2f(unsigned short u) {
  union { unsigned u; float f; } v; v.u = ((unsigned)u) << 16;
  return v.f;
}

#define GLOAD16(g, l)                                                    \
  __builtin_amdgcn_global_load_lds(                                      \
      (const __attribute__((address_space(1))) unsigned int*)(g),        \
      (__attribute__((address_space(3))) unsigned int*)(l), 16, 0, 0)

// ---------- f32 -> bf16 conversion (memory-bound) ----------
__global__ __launch_bounds__(256) void cvt_f32_bf16(
    const float* __restrict__ in, unsigned short* __restrict__ out, long n) {
  long i = ((long)blockIdx.x * 256 + threadIdx.x) * 8;
  if (i >= n) return;
  const float4* p = (const float4*)(in + i);
  float4 a = p[0], b = p[1];
  short8 r;
  r[0] = (short)f2bf(a.x); r[1] = (short)f2bf(a.y);
  r[2] = (short)f2bf(a.z); r[3] = (short)f2bf(a.w);
  r[4] = (short)f2bf(b.x); r[5] = (short)f2bf(b.y);
  r[6] = (short)f2bf(b.z); r[7] = (short)f2bf(b.w);
  *(short8*)(out + i) = r;
}

// ---------- gemm_bt: C[b][m,n] = scale * sum_k A[b][m,k]*B[b][n,k] ----------
// A: [M,K] bf16 row-major (lda elems), B: [N,K] bf16 row-major (ldb elems).
// blockIdx.y = batch; asb/bsb/csb are per-batch strides in ELEMENTS.
// 128x128 tile, 4 waves (2x2), BK=64, 16x16x32 bf16 MFMA.
// LDS XOR-swizzle: slot-col ^= (row&7); applied on stage-SOURCE and on READ.
template <bool OUT_BF16>
__global__ __launch_bounds__(256) void gemm_bt(
    const unsigned short* __restrict__ A, int lda, size_t asb,
    const unsigned short* __restrict__ B, int ldb, size_t bsb,
    void* __restrict__ C, int ldc, size_t csb,
    int nbn, int K, float scale) {
  __shared__ unsigned short As[128 * 64];
  __shared__ unsigned short Bs[128 * 64];

  A += (size_t)blockIdx.y * asb;
  B += (size_t)blockIdx.y * bsb;
  char* Cb = (char*)C + (size_t)blockIdx.y * csb * (OUT_BF16 ? 2 : 4);

  // XCD-aware swizzle (grid.x always a multiple of 8 here)
  unsigned bid = blockIdx.x;
  unsigned cpx = gridDim.x >> 3;
  unsigned swz = (bid & 7u) * cpx + (bid >> 3);
  int bm = (int)(swz / (unsigned)nbn);
  int bn = (int)(swz % (unsigned)nbn);
  int m0 = bm * 128, n0 = bn * 128;

  int t = threadIdx.x;
  int lane = t & 63, wid = t >> 6;
  int wm = wid >> 1, wn = wid & 1;
  int l15 = lane & 15, l4 = lane >> 4;

  // staging: chunk c = i*256 + t ; row = c>>3 (=32*i + t>>3), slot col = c&7
  int srow = t >> 3;
  int scol = t & 7;
  int g = scol ^ (srow & 7);  // inverse-swizzled global chunk col
  const unsigned short* pa = A + (size_t)(m0 + srow) * lda + g * 8;
  const unsigned short* pb = B + (size_t)(n0 + srow) * ldb + g * 8;

  f32x4 acc[4][4] = {};

  for (int k0 = 0; k0 < K; k0 += 64) {
    __syncthreads();
#pragma unroll
    for (int i = 0; i < 4; i++) {
      GLOAD16(pa + (size_t)(32 * i) * lda + k0,
              (char*)As + (size_t)(i * 256 + wid * 64) * 16);
      GLOAD16(pb + (size_t)(32 * i) * ldb + k0,
              (char*)Bs + (size_t)(i * 256 + wid * 64) * 16);
    }
    __syncthreads();
#pragma unroll
    for (int ks = 0; ks < 2; ks++) {
      short8 af[4], bfr[4];
#pragma unroll
      for (int mi = 0; mi < 4; mi++) {
        int r = wm * 64 + mi * 16 + l15;
        int c = ((ks << 2) | l4) ^ (r & 7);
        af[mi] = *(const short8*)((const char*)As + r * 128 + c * 16);
      }
#pragma unroll
      for (int ni = 0; ni < 4; ni++) {
        int r = wn * 64 + ni * 16 + l15;
        int c = ((ks << 2) | l4) ^ (r & 7);
        bfr[ni] = *(const short8*)((const char*)Bs + r * 128 + c * 16);
      }
#pragma unroll
      for (int mi = 0; mi < 4; mi++)
#pragma unroll
        for (int ni = 0; ni < 4; ni++)
          acc[mi][ni] = __builtin_amdgcn_mfma_f32_16x16x32_bf16(
              af[mi], bfr[ni], acc[mi][ni], 0, 0, 0);
    }
  }

#pragma unroll
  for (int mi = 0; mi < 4; mi++)
#pragma unroll
    for (int ni = 0; ni < 4; ni++)
#pragma unroll
      for (int j = 0; j < 4; j++) {
        int row = m0 + wm * 64 + mi * 16 + l4 * 4 + j;
        int col = n0 + wn * 64 + ni * 16 + l15;
        float val = acc[mi][ni][j] * scale;
        if constexpr (OUT_BF16)
          ((unsigned short*)Cb)[(size_t)row * ldc + col] = f2bf(val);
        else
          ((float*)Cb)[(size_t)row * ldc + col] = val;
      }
}

// ---------- row softmax over bf16 matrix, in place ----------
// one block per row; 256 threads x 16 elems = 4096 cols
__global__ __launch_bounds__(256) void softmax_rows(unsigned short* S, int ncols) {
  __shared__ float red[8];
  int row = blockIdx.x;
  unsigned short* p = S + (size_t)row * ncols;
  int t = threadIdx.x;
  int lane = t & 63, wid = t >> 6;

  short8 h0 = ((short8*)p)[t * 2];
  short8 h1 = ((short8*)p)[t * 2 + 1];
  float v[16];
#pragma unroll
  for (int j = 0; j < 8; j++) {
    v[j] = bf2f((unsigned short)h0[j]);
    v[8 + j] = bf2f((unsigned short)h1[j]);
  }
  float m = v[0];
#pragma unroll
  for (int j = 1; j < 16; j++) m = fmaxf(m, v[j]);
#pragma unroll
  for (int off = 1; off < 64; off <<= 1) m = fmaxf(m, __shfl_xor(m, off));
  if (lane == 0) red[wid] = m;
  __syncthreads();
  m = fmaxf(fmaxf(red[0], red[1]), fmaxf(red[2], red[3]));

  float e[16], s = 0.f;
#pragma unroll
  for (int j = 0; j < 16; j++) { e[j] = __expf(v[j] - m); s += e[j]; }
#pragma unroll
  for (int off = 1; off < 64; off <<= 1) s += __shfl_xor(s, off);
  if (lane == 0) red[4 + wid] = s;
  __syncthreads();
  float inv = 1.0f / (red[4] + red[5] + red[6] + red[7]);

  short8 o0, o1;
#pragma unroll
  for (int j = 0; j < 8; j++) {
    o0[j] = (short)f2bf(e[j] * inv);
    o1[j] = (short)f2bf(e[8 + j] * inv);
  }
  ((short8*)p)[t * 2] = o0;
  ((short8*)p)[t * 2 + 1] = o1;
}

// ---------- launcher ----------
extern "C" void kernel_launch(void* const* d_in, const int* in_sizes, int n_in,
                              void* d_out, int out_size, void* d_ws, size_t ws_size,
                              hipStream_t stream) {
  (void)in_sizes; (void)n_in; (void)out_size;
  const float* x  = (const float*)d_in[0];
  const float* Wq = (const float*)d_in[1];
  const float* Wk = (const float*)d_in[2];
  const float* Wv = (const float*)d_in[3];
  float* out = (float*)d_out;

  const int Bn = 4, S = 4096, D = 1024;
  const size_t MS = (size_t)Bn * S;  // 16384
  const float scale = 0.03125f;      // 1/sqrt(1024)

  // ---- workspace layout ----
  // QKb  [16384, 2048] bf16 : 64 MiB
  // VTb  [1024, 16384] bf16 : 32 MiB
  // Sreg : batched -> [4,S,S] bf16 (128 MiB) ; serial -> [S,S] bf16 (32 MiB)
  //        (xb [16384,1024] bf16 = 32 MiB is aliased into Sreg: dead before
  //         any scores write)
  // wqkb [2048,1024] bf16 : 4 MiB ; wvb [1024,1024] bf16 : 2 MiB
  char* ws = (char*)d_ws;
  unsigned short* QKb = (unsigned short*)ws; ws += MS * 2048 * 2;
  unsigned short* VTb = (unsigned short*)ws; ws += MS * D * 2;
  unsigned short* Sreg = (unsigned short*)ws;
  const size_t s4_bytes = (size_t)Bn * S * S * 2;
  const size_t s1_bytes = (size_t)S * S * 2;
  size_t head = (size_t)(ws - (char*)d_ws);
  bool batched = ws_size >= head + s4_bytes + 6u * 1024 * 1024;
  ws += batched ? s4_bytes : s1_bytes;
  unsigned short* wqkb = (unsigned short*)ws; ws += (size_t)2048 * D * 2;
  unsigned short* wvb  = (unsigned short*)ws;
  unsigned short* xb = Sreg;  // alias

  // convert inputs to bf16
  cvt_f32_bf16<<<8192, 256, 0, stream>>>(x, xb, (long)MS * D);
  cvt_f32_bf16<<<512, 256, 0, stream>>>(Wq, wqkb, (long)D * D);
  cvt_f32_bf16<<<512, 256, 0, stream>>>(Wk, wqkb + (size_t)D * D, (long)D * D);
  cvt_f32_bf16<<<512, 256, 0, stream>>>(Wv, wvb, (long)D * D);

  // QK = x @ [Wq;Wk]^T  (M=16384, N=2048, K=1024) -> QKb [16384,2048]
  gemm_bt<true><<<dim3(2048, 1), 256, 0, stream>>>(
      xb, D, 0, wqkb, D, 0, QKb, 2048, 0, 16, D, 1.0f);
  // VT = Wv @ x^T  (M=1024, N=16384, K=1024) -> VTb [1024,16384]
  gemm_bt<true><<<dim3(1024, 1), 256, 0, stream>>>(
      wvb, D, 0, xb, D, 0, VTb, (int)MS, 0, 128, D, 1.0f);

  if (batched) {
    // scores[b] = Q_b K_b^T * scale  (M=N=4096, K=1024) -> bf16
    gemm_bt<true><<<dim3(1024, Bn), 256, 0, stream>>>(
        QKb, 2048, (size_t)S * 2048,
        QKb + 1024, 2048, (size_t)S * 2048,
        Sreg, S, (size_t)S * S, 32, D, scale);
    softmax_rows<<<(int)MS, 256, 0, stream>>>(Sreg, S);
    // out[b] = P_b @ V_b  via B'[n,k] = VT[n, b*S+k]  (M=4096,N=1024,K=4096)
    gemm_bt<false><<<dim3(256, Bn), 256, 0, stream>>>(
        Sreg, S, (size_t)S * S,
        VTb, (int)MS, (size_t)S,
        out, D, (size_t)S * D, 8, S, 1.0f);
  } else {
    for (int b = 0; b < Bn; b++) {
      const unsigned short* Qx = QKb + (size_t)b * S * 2048;
      const unsigned short* Kx = Qx + 1024;
      gemm_bt<true><<<dim3(1024, 1), 256, 0, stream>>>(
          Qx, 2048, 0, Kx, 2048, 0, Sreg, S, 0, 32, D, scale);
      softmax_rows<<<S, 256, 0, stream>>>(Sreg, S);
      gemm_bt<false><<<dim3(256, 1), 256, 0, stream>>>(
          Sreg, S, 0, VTb + (size_t)b * S, (int)MS, 0,
          out + (size_t)b * S * D, D, 0, 8, S, 1.0f);
    }
  }
}

// Round 3
// 464.523 us; speedup vs baseline: 1.5247x; 1.1514x over previous
//
#include <hip/hip_runtime.h>
#include <cstdint>
#include <cstddef>

typedef __attribute__((ext_vector_type(8))) short short8;
typedef __attribute__((ext_vector_type(4))) float f32x4;

// ---------- helpers ----------
__device__ __forceinline__ unsigned short f2bf(float x) {
  union { float f; unsigned u; } v; v.f = x;
  unsigned r = (v.u + 0x7FFFu + ((v.u >> 16) & 1u)) >> 16;
  return (unsigned short)r;
}
__device__ __forceinline__ float bf2f(unsigned short u) {
  union { unsigned u; float f; } v; v.u = ((unsigned)u) << 16;
  return v.f;
}

#define GLOAD16(g, l)                                                    \
  __builtin_amdgcn_global_load_lds(                                      \
      (const __attribute__((address_space(1))) unsigned int*)(g),        \
      (__attribute__((address_space(3))) unsigned int*)(l), 16, 0, 0)

// ---------- f32 -> bf16 conversion (memory-bound) ----------
__global__ __launch_bounds__(256) void cvt_f32_bf16(
    const float* __restrict__ in, unsigned short* __restrict__ out, long n) {
  long i = ((long)blockIdx.x * 256 + threadIdx.x) * 8;
  if (i >= n) return;
  const float4* p = (const float4*)(in + i);
  float4 a = p[0], b = p[1];
  short8 r;
  r[0] = (short)f2bf(a.x); r[1] = (short)f2bf(a.y);
  r[2] = (short)f2bf(a.z); r[3] = (short)f2bf(a.w);
  r[4] = (short)f2bf(b.x); r[5] = (short)f2bf(b.y);
  r[6] = (short)f2bf(b.z); r[7] = (short)f2bf(b.w);
  *(short8*)(out + i) = r;
}

// ---------- gemm_bt256: C[b][m,n] = scale * sum_k A[b][m,k]*B[b][n,k] ----
// 256x256 tile, 8 waves (2M x 4N), BK=64, double-buffered LDS (128 KiB),
// counted vmcnt(8) (next tile's loads stay in flight across barriers),
// raw s_barrier, setprio around MFMA clusters.
// LDS swizzle: 16B chunk slot ^= (row&7); inverse applied on global source.
// Requires M%256==0, N%256==0, K%64==0, gridDim.x%8==0.
template <bool OUT_BF16>
__global__ __launch_bounds__(512, 2) void gemm_bt256(
    const unsigned short* __restrict__ A, int lda, size_t asb,
    const unsigned short* __restrict__ B, int ldb, size_t bsb,
    void* __restrict__ C, int ldc, size_t csb,
    int nbn, int K, float scale) {
  __shared__ unsigned short As[2][256 * 64];
  __shared__ unsigned short Bs[2][256 * 64];

  A += (size_t)blockIdx.y * asb;
  B += (size_t)blockIdx.y * bsb;
  char* Cb = (char*)C + (size_t)blockIdx.y * csb * (OUT_BF16 ? 2 : 4);

  // XCD-aware block swizzle (gridDim.x multiple of 8)
  unsigned bid = blockIdx.x;
  unsigned cpx = gridDim.x >> 3;
  unsigned swz = (bid & 7u) * cpx + (bid >> 3);
  int bm = (int)(swz / (unsigned)nbn);
  int bn = (int)(swz % (unsigned)nbn);
  int m0 = bm * 256, n0 = bn * 256;

  int t512 = threadIdx.x;
  int lane = t512 & 63, wid = t512 >> 6;
  int wm = wid >> 2, wn = wid & 3;           // 2 x 4 wave grid
  int l15 = lane & 15, l4 = lane >> 4;

  // staging: thread t handles 16B chunk (i*512+t): row = i*64 + (t>>3),
  // LDS slot = t&7 (linear dest), global chunk = slot ^ (row&7).
  int srow = t512 >> 3;
  int g = (t512 & 7) ^ ((t512 >> 3) & 7);
  const unsigned short* pa = A + (size_t)(m0 + srow) * lda + g * 8;
  const unsigned short* pb = B + (size_t)(n0 + srow) * ldb + g * 8;

  f32x4 acc[8][4] = {};

  const int NT = K >> 6;

  // prologue: stage tile 0 into buffer 0
#pragma unroll
  for (int i = 0; i < 4; i++)
    GLOAD16(pa + (size_t)(i * 64) * lda, (char*)As[0] + i * 8192 + t512 * 16);
#pragma unroll
  for (int i = 0; i < 4; i++)
    GLOAD16(pb + (size_t)(i * 64) * ldb, (char*)Bs[0] + i * 8192 + t512 * 16);

  for (int t = 0; t < NT; ++t) {
    int cur = t & 1;
    // barrier A: all waves finished reading buf[cur^1] (tile t-1)
    __builtin_amdgcn_s_barrier();
    if (t + 1 < NT) {
      int k0 = (t + 1) << 6;
#pragma unroll
      for (int i = 0; i < 4; i++)
        GLOAD16(pa + (size_t)(i * 64) * lda + k0,
                (char*)As[cur ^ 1] + i * 8192 + t512 * 16);
#pragma unroll
      for (int i = 0; i < 4; i++)
        GLOAD16(pb + (size_t)(i * 64) * ldb + k0,
                (char*)Bs[cur ^ 1] + i * 8192 + t512 * 16);
      // wait ONLY for tile t's 8 loads; the 8 just issued stay in flight
      asm volatile("s_waitcnt vmcnt(8)" ::: "memory");
    } else {
      asm volatile("s_waitcnt vmcnt(0)" ::: "memory");
    }
    // barrier B: every wave's tile-t loads have landed
    __builtin_amdgcn_s_barrier();

    const char* Ab = (const char*)As[cur];
    const char* Bb = (const char*)Bs[cur];

    // B fragments for the whole tile (4 n-frags x 2 k-slices)
    short8 bfv[4][2];
#pragma unroll
    for (int ni = 0; ni < 4; ni++)
#pragma unroll
      for (int ks = 0; ks < 2; ks++) {
        int r = wn * 64 + ni * 16 + l15;
        int c = ((ks << 2) | l4) ^ (r & 7);
        bfv[ni][ks] = *(const short8*)(Bb + r * 128 + c * 16);
      }

#pragma unroll
    for (int q = 0; q < 4; ++q) {
      short8 afv[2][2];
#pragma unroll
      for (int m2 = 0; m2 < 2; m2++)
#pragma unroll
        for (int ks = 0; ks < 2; ks++) {
          int r = wm * 128 + (q * 2 + m2) * 16 + l15;
          int c = ((ks << 2) | l4) ^ (r & 7);
          afv[m2][ks] = *(const short8*)(Ab + r * 128 + c * 16);
        }
      asm volatile("s_waitcnt lgkmcnt(0)" ::: "memory");
      __builtin_amdgcn_sched_barrier(0);
      __builtin_amdgcn_s_setprio(1);
#pragma unroll
      for (int ks = 0; ks < 2; ks++)
#pragma unroll
        for (int m2 = 0; m2 < 2; m2++)
#pragma unroll
          for (int ni = 0; ni < 4; ni++)
            acc[q * 2 + m2][ni] = __builtin_amdgcn_mfma_f32_16x16x32_bf16(
                afv[m2][ks], bfv[ni][ks], acc[q * 2 + m2][ni], 0, 0, 0);
      __builtin_amdgcn_s_setprio(0);
    }
  }

  // epilogue
#pragma unroll
  for (int mi = 0; mi < 8; mi++)
#pragma unroll
    for (int ni = 0; ni < 4; ni++)
#pragma unroll
      for (int j = 0; j < 4; j++) {
        int row = m0 + wm * 128 + mi * 16 + l4 * 4 + j;
        int col = n0 + wn * 64 + ni * 16 + l15;
        float val = acc[mi][ni][j] * scale;
        if constexpr (OUT_BF16)
          ((unsigned short*)Cb)[(size_t)row * ldc + col] = f2bf(val);
        else
          ((float*)Cb)[(size_t)row * ldc + col] = val;
      }
}

// ---------- row softmax over bf16 matrix, in place ----------
__global__ __launch_bounds__(256) void softmax_rows(unsigned short* S, int ncols) {
  __shared__ float red[8];
  int row = blockIdx.x;
  unsigned short* p = S + (size_t)row * ncols;
  int t = threadIdx.x;
  int lane = t & 63, wid = t >> 6;

  short8 h0 = ((short8*)p)[t * 2];
  short8 h1 = ((short8*)p)[t * 2 + 1];
  float v[16];
#pragma unroll
  for (int j = 0; j < 8; j++) {
    v[j] = bf2f((unsigned short)h0[j]);
    v[8 + j] = bf2f((unsigned short)h1[j]);
  }
  float m = v[0];
#pragma unroll
  for (int j = 1; j < 16; j++) m = fmaxf(m, v[j]);
#pragma unroll
  for (int off = 1; off < 64; off <<= 1) m = fmaxf(m, __shfl_xor(m, off));
  if (lane == 0) red[wid] = m;
  __syncthreads();
  m = fmaxf(fmaxf(red[0], red[1]), fmaxf(red[2], red[3]));

  float e[16], s = 0.f;
#pragma unroll
  for (int j = 0; j < 16; j++) { e[j] = __expf(v[j] - m); s += e[j]; }
#pragma unroll
  for (int off = 1; off < 64; off <<= 1) s += __shfl_xor(s, off);
  if (lane == 0) red[4 + wid] = s;
  __syncthreads();
  float inv = 1.0f / (red[4] + red[5] + red[6] + red[7]);

  short8 o0, o1;
#pragma unroll
  for (int j = 0; j < 8; j++) {
    o0[j] = (short)f2bf(e[j] * inv);
    o1[j] = (short)f2bf(e[8 + j] * inv);
  }
  ((short8*)p)[t * 2] = o0;
  ((short8*)p)[t * 2 + 1] = o1;
}

// ---------- launcher ----------
extern "C" void kernel_launch(void* const* d_in, const int* in_sizes, int n_in,
                              void* d_out, int out_size, void* d_ws, size_t ws_size,
                              hipStream_t stream) {
  (void)in_sizes; (void)n_in; (void)out_size;
  const float* x  = (const float*)d_in[0];
  const float* Wq = (const float*)d_in[1];
  const float* Wk = (const float*)d_in[2];
  const float* Wv = (const float*)d_in[3];
  float* out = (float*)d_out;

  const int Bn = 4, S = 4096, D = 1024;
  const size_t MS = (size_t)Bn * S;  // 16384
  const float scale = 0.03125f;      // 1/sqrt(1024)

  // ---- workspace layout ----
  char* ws = (char*)d_ws;
  unsigned short* QKb = (unsigned short*)ws; ws += MS * 2048 * 2;        // 64 MiB
  unsigned short* VTb = (unsigned short*)ws; ws += MS * D * 2;           // 32 MiB
  unsigned short* Sreg = (unsigned short*)ws;
  const size_t s4_bytes = (size_t)Bn * S * S * 2;   // 128 MiB
  const size_t s1_bytes = (size_t)S * S * 2;        // 32 MiB
  size_t head = (size_t)(ws - (char*)d_ws);
  bool batched = ws_size >= head + s4_bytes + 6u * 1024 * 1024;
  ws += batched ? s4_bytes : s1_bytes;
  unsigned short* wqkb = (unsigned short*)ws; ws += (size_t)2048 * D * 2;
  unsigned short* wvb  = (unsigned short*)ws;
  unsigned short* xb = Sreg;  // alias: xb dead before any scores write

  // convert inputs to bf16
  cvt_f32_bf16<<<8192, 256, 0, stream>>>(x, xb, (long)MS * D);
  cvt_f32_bf16<<<512, 256, 0, stream>>>(Wq, wqkb, (long)D * D);
  cvt_f32_bf16<<<512, 256, 0, stream>>>(Wk, wqkb + (size_t)D * D, (long)D * D);
  cvt_f32_bf16<<<512, 256, 0, stream>>>(Wv, wvb, (long)D * D);

  // QK = x @ [Wq;Wk]^T  (M=16384, N=2048, K=1024)
  gemm_bt256<true><<<dim3(512, 1), 512, 0, stream>>>(
      xb, D, 0, wqkb, D, 0, QKb, 2048, 0, 8, D, 1.0f);
  // VT = Wv @ x^T  (M=1024, N=16384, K=1024) -> VTb [1024,16384]
  gemm_bt256<true><<<dim3(256, 1), 512, 0, stream>>>(
      wvb, D, 0, xb, D, 0, VTb, (int)MS, 0, 64, D, 1.0f);

  if (batched) {
    // scores[b] = Q_b K_b^T * scale  (M=N=4096, K=1024)
    gemm_bt256<true><<<dim3(256, Bn), 512, 0, stream>>>(
        QKb, 2048, (size_t)S * 2048,
        QKb + 1024, 2048, (size_t)S * 2048,
        Sreg, S, (size_t)S * S, 16, D, scale);
    softmax_rows<<<(int)MS, 256, 0, stream>>>(Sreg, S);
    // out[b] = P_b @ V_b  (M=4096, N=1024, K=4096)
    gemm_bt256<false><<<dim3(64, Bn), 512, 0, stream>>>(
        Sreg, S, (size_t)S * S,
        VTb, (int)MS, (size_t)S,
        out, D, (size_t)S * D, 4, S, 1.0f);
  } else {
    for (int b = 0; b < Bn; b++) {
      const unsigned short* Qx = QKb + (size_t)b * S * 2048;
      const unsigned short* Kx = Qx + 1024;
      gemm_bt256<true><<<dim3(256, 1), 512, 0, stream>>>(
          Qx, 2048, 0, Kx, 2048, 0, Sreg, S, 0, 16, D, scale);
      softmax_rows<<<S, 256, 0, stream>>>(Sreg, S);
      gemm_bt256<false><<<dim3(64, 1), 512, 0, stream>>>(
          Sreg, S, 0, VTb + (size_t)b * S, (int)MS, 0,
          out + (size_t)b * S * D, D, 0, 4, S, 1.0f);
    }
  }
}